// Round 8
// baseline (316.244 us; speedup 1.0000x reference)
//
#include <hip/hip_runtime.h>
#include <cfloat>
#include <cstdint>

// Problem constants
#define NROWS 131072
#define DIMD  128
#define KCODE 1024
#define MARGIN 0.045f  // f16 single-pass gap error sigma ~9.6e-3 -> ~4.7 sigma
#define RCAP  65536    // refine capacity (pairs) in the N-int WS_REFINE region

typedef __attribute__((ext_vector_type(8))) _Float16 half8;  // 8 f16 = 4 VGPRs
typedef __attribute__((ext_vector_type(4))) float f32x4;

union U4H8 { uint4 u; half8 h; };

// ---- workspace layout (bytes); total ~3.23 MB ----
#define WS_REFINE_CNT 0         // int
#define WS_LOSS       8         // float (unused slot; layout stability)
#define WS_COUNTS     16        // int[1024]
#define WS_SUMS       4608      // float[K*D] = 512 KB (layout [k][d])
#define WS_LPART      528896    // float[256] loss partial slots (zeroed)
#define WS_CURSOR     532992    // int[1024]
#define WS_E2         537088    // float[1024]
#define WS_ZERO_BYTES 541184    // memset [0, WS_ZERO_BYTES) — covers e2 too
#define WS_ET         541184    // float[K*D] (ET[k][d])
#define WS_BHI        1065472   // uint4[16384] = 256 KB (f16 B fragments)
#define WS_BEST       1327616   // (unused; layout stability)
#define WS_IDX        1589760   // int[N]
#define WS_ROWLIST    2114048   // int[N]
#define WS_REFINE     2638336   // int[N] -> used as (row,i2) pairs, cap 65536
#define WS_PARTIALS   3162624   // float[16384] (unused; layout stability)
// end: 3228160 bytes

// ---- output offsets (in floats), reference return order ----
#define OUT_QST  ((size_t)0)
#define OUT_EMB  ((size_t)NROWS * DIMD)
#define OUT_CNT  (OUT_EMB + (size_t)DIMD * KCODE)
#define OUT_ES   (OUT_CNT + KCODE)
#define OUT_LOSS (OUT_ES + (size_t)DIMD * KCODE)

__device__ __forceinline__ unsigned f16pair(float a, float b) {
    union { _Float16 h[2]; unsigned u; } p;
    p.h[0] = (_Float16)a;
    p.h[1] = (_Float16)b;
    return p.u;
}

// ============================================================
// Fused prep: one pass over E producing (1) Bh MFMA B-fragments (f16),
// (2) ET[k][d] transpose, (3) e2[k] = sum_d E[d][k]^2 via atomics.
__global__ void vq_prep(const float* __restrict__ E, uint4* __restrict__ Bh,
                        float* __restrict__ ET, float* __restrict__ e2) {
    int gid = blockIdx.x * 256 + threadIdx.x;   // 0..16383 == fi
    int l = gid & 63;
    int t = (gid >> 6) & 3;
    int NB = gid >> 8;
    int n = NB * 16 + (l & 15);
    int k0 = t * 32 + (l >> 4) * 8;
    float v[8];
    float ss = 0.f;
    #pragma unroll
    for (int j = 0; j < 8; ++j) {
        v[j] = E[(size_t)(k0 + j) * KCODE + n];
        ss = fmaf(v[j], v[j], ss);
    }
    Bh[gid] = make_uint4(f16pair(v[0], v[1]), f16pair(v[2], v[3]),
                         f16pair(v[4], v[5]), f16pair(v[6], v[7]));
    float4* et4 = (float4*)(ET + (size_t)n * DIMD + k0);
    et4[0] = make_float4(v[0], v[1], v[2], v[3]);
    et4[1] = make_float4(v[4], v[5], v[6], v[7]);
    atomicAdd(&e2[n], ss);
}

// ============================================================
// Main kernel: per-row argmin_k ( ||e_k||^2 - 2 x.e_k ) via SINGLE-PASS f16
// MFMA. 256 threads = 4 waves, each wave owns ONE 16-row m-tile, grid =
// NROWS/64 = 2048 blocks -> up to 8 blocks/CU = 32 waves/CU (round-7
// counters: occupancy 34% grid-capped at 16 waves/CU, VALU only 52% busy).
// launch_bounds(256,6) caps VGPR at 85 >> ~50 needed — no round-4 spill
// risk. Tracks (m1,i1,m2,i2) per row; ambiguous rows get a top-2 exact
// fp32 re-check in vq_refine2. No K-loop barriers; B register
// double-buffered straight from global (B is 256 KB, L2-resident).

#define LOADB(bARR, ev_, nb_)                                     \
  { _Pragma("unroll")                                             \
    for (int t_ = 0; t_ < 4; ++t_)                                \
      bARR[t_] = Bh[((nb_) * 4 + t_) * 64 + l];                   \
    ev_ = e2[(nb_) * 16 + m]; }

#define COMPUTE_NB(nb_, bARR, ev_)                                           \
  {                                                                          \
    f32x4 acc = (f32x4){0.f, 0.f, 0.f, 0.f};                                 \
    _Pragma("unroll")                                                        \
    for (int t_ = 0; t_ < 4; ++t_) {                                         \
      U4H8 bh_; bh_.u = bARR[t_];                                            \
      acc = __builtin_amdgcn_mfma_f32_16x16x32_f16(ah[t_], bh_.h,            \
                                                   acc, 0, 0, 0);            \
    }                                                                        \
    int col_ = (nb_) * 16 + m;                                               \
    _Pragma("unroll")                                                        \
    for (int r_ = 0; r_ < 4; ++r_) {                                         \
      float s_ = fmaf(-2.0f, acc[r_], ev_);                                  \
      if (s_ < m1[r_]) {                                                     \
        m2[r_] = m1[r_]; i2[r_] = i1[r_];                                    \
        m1[r_] = s_;     i1[r_] = col_;                                      \
      } else if (s_ < m2[r_]) {                                              \
        m2[r_] = s_;     i2[r_] = col_;                                      \
      }                                                                      \
    }                                                                        \
  }

__global__ __launch_bounds__(256, 6) void vq_argmin_mfma(
        const float* __restrict__ x, const uint4* __restrict__ Bh,
        const float* __restrict__ e2,
        int* __restrict__ idx, int* __restrict__ counts,
        int* __restrict__ refine_pairs, int* __restrict__ refine_cnt) {

    __shared__ int hist[KCODE];   // 4 KB (epilogue only)

    const int tid = threadIdx.x;
    const int w = tid >> 6, l = tid & 63;
    const int m = l & 15, q = l >> 4;
    const int rw = blockIdx.x * 64 + w * 16;

    // B prefetch prologue (in flight while the A-phase loads/converts)
    uint4 bA[4], bB[4];
    float evA, evB;
    LOADB(bA, evA, 0);
    LOADB(bB, evB, 1);

    // ---------- A-phase: f16 A-fragments straight from global ----------
    // lane (m,q) holds x[rw+m][t*32 + q*8 + j], j=0..7
    const float4* x4 = (const float4*)x;
    half8 ah[4];                    // [k-tile]
    {
        int row = rw + m;
        #pragma unroll
        for (int t = 0; t < 4; ++t) {
            int c4 = t * 8 + q * 2;
            float4 va = x4[(size_t)row * 32 + c4];
            float4 vb = x4[(size_t)row * 32 + c4 + 1];
            half8 hh;
            hh[0] = (_Float16)va.x; hh[1] = (_Float16)va.y;
            hh[2] = (_Float16)va.z; hh[3] = (_Float16)va.w;
            hh[4] = (_Float16)vb.x; hh[5] = (_Float16)vb.y;
            hh[6] = (_Float16)vb.z; hh[7] = (_Float16)vb.w;
            ah[t] = hh;
        }
    }

    float m1[4], m2[4];
    int i1[4], i2[4];
    #pragma unroll
    for (int r = 0; r < 4; ++r) {
        m1[r] = FLT_MAX; m2[r] = FLT_MAX;
        i1[r] = 0; i2[r] = 0;
    }

    // ---------- K-loop over 64 n-blocks of 16 codes, barrier-free ----------
    for (int nb = 0; nb < 64; nb += 2) {
        COMPUTE_NB(nb, bA, evA);
        { int p = (nb + 2 <= 63) ? nb + 2 : 62; LOADB(bA, evA, p); }
        COMPUTE_NB(nb + 1, bB, evB);
        { int p = (nb + 3 <= 63) ? nb + 3 : 63; LOADB(bB, evB, p); }
    }

    // ---------- merge across the 16 lanes of each quad ----------
    // Full (m1,i1,m2,i2) lexicographic merge.
    #pragma unroll
    for (int r = 0; r < 4; ++r) {
        float a1 = m1[r], a2 = m2[r];
        int ai1 = i1[r], ai2 = i2[r];
        #pragma unroll
        for (int off = 1; off < 16; off <<= 1) {
            float o1 = __shfl_xor(a1, off, 64);
            float o2 = __shfl_xor(a2, off, 64);
            int oi1 = __shfl_xor(ai1, off, 64);
            int oi2 = __shfl_xor(ai2, off, 64);
            // winner of firsts (lex, first-index ties)
            bool take = (o1 < a1) || (o1 == a1 && oi1 < ai1);
            float w1 = take ? o1 : a1;  int wi1 = take ? oi1 : ai1;
            float l1 = take ? a1 : o1;  int li1 = take ? ai1 : oi1;
            // second = lexmin{ (a2,ai2), (o2,oi2), (l1,li1) }
            float c2 = a2; int ci2 = ai2;
            if (o2 < c2 || (o2 == c2 && oi2 < ci2)) { c2 = o2; ci2 = oi2; }
            if (l1 < c2 || (l1 == c2 && li1 < ci2)) { c2 = l1; ci2 = li1; }
            a1 = w1; ai1 = wi1; a2 = c2; ai2 = ci2;
        }
        m1[r] = a1; m2[r] = a2;
        i1[r] = ai1; i2[r] = ai2;
    }

    // ---------- write idx, LDS-aggregated histogram, refine pairs ----------
    for (int i = tid; i < KCODE; i += 256) hist[i] = 0;
    __syncthreads();
    if (m == 0) {   // 4 representative lanes per wave (one per quad)
        #pragma unroll
        for (int r = 0; r < 4; ++r) {
            int row = rw + q * 4 + r;
            int bi = i1[r];
            idx[row] = bi;
            atomicAdd(&hist[bi], 1);
            if (!(m2[r] - m1[r] > MARGIN)) {
                int pos = atomicAdd(refine_cnt, 1);
                if (pos < RCAP) {
                    refine_pairs[2 * pos]     = row;
                    refine_pairs[2 * pos + 1] = i2[r];
                }
            }
        }
    }
    __syncthreads();
    for (int i = tid; i < KCODE; i += 256) {
        int h = hist[i];
        if (h) atomicAdd(&counts[i], h);
    }
}

// ============================================================
// Top-2 exact re-check: for each ambiguous row, compute exact fp32 distances
// for the two f16 candidates (ET rows are contiguous 512 B) and keep the
// lex-min. O(cnt * 256 FMA). Thread-per-entry, no LDS.
__global__ __launch_bounds__(256) void vq_refine2(
        const float* __restrict__ x, const float* __restrict__ ET,
        const float* __restrict__ e2,
        const int* __restrict__ refine_pairs, const int* __restrict__ refine_cnt,
        int* __restrict__ idx, int* __restrict__ counts) {
    int cnt = *refine_cnt;
    if (cnt > RCAP) cnt = RCAP;
    for (int e = blockIdx.x * 256 + threadIdx.x; e < cnt; e += gridDim.x * 256) {
        int n  = refine_pairs[2 * e];
        int kb = refine_pairs[2 * e + 1];
        int ka = idx[n];
        const float4* xa = (const float4*)(x + (size_t)n * DIMD);
        const float4* ea = (const float4*)(ET + (size_t)ka * DIMD);
        const float4* eb = (const float4*)(ET + (size_t)kb * DIMD);
        float da = 0.f, db = 0.f;
        #pragma unroll 8
        for (int d4 = 0; d4 < DIMD / 4; ++d4) {
            float4 xv = xa[d4];
            float4 av = ea[d4];
            float4 bv = eb[d4];
            da = fmaf(xv.x, av.x, da); da = fmaf(xv.y, av.y, da);
            da = fmaf(xv.z, av.z, da); da = fmaf(xv.w, av.w, da);
            db = fmaf(xv.x, bv.x, db); db = fmaf(xv.y, bv.y, db);
            db = fmaf(xv.z, bv.z, db); db = fmaf(xv.w, bv.w, db);
        }
        float sa = fmaf(-2.0f, da, e2[ka]);
        float sb = fmaf(-2.0f, db, e2[kb]);
        bool swap = (sb < sa) || (sb == sa && kb < ka);   // first-index ties
        if (swap) {
            idx[n] = kb;
            atomicSub(&counts[ka], 1);
            atomicAdd(&counts[kb], 1);
        }
    }
}

// ============================================================
__global__ void vq_scan(const int* __restrict__ counts, int* __restrict__ cursor) {
    __shared__ int s[KCODE];
    int t = threadIdx.x;
    int c = counts[t];
    s[t] = c;
    __syncthreads();
    for (int off = 1; off < KCODE; off <<= 1) {
        int v = (t >= off) ? s[t - off] : 0;
        __syncthreads();
        s[t] += v;
        __syncthreads();
    }
    cursor[t] = s[t] - c;
}

// LDS-aggregated bucket fill (kills same-address global atomic chains)
__global__ void vq_fill(const int* __restrict__ idx, int* __restrict__ cursor,
                        int* __restrict__ rowlist) {
    __shared__ int hcnt[KCODE];
    __shared__ int hbase[KCODE];
    int tid = threadIdx.x;
    for (int i = tid; i < KCODE; i += 256) hcnt[i] = 0;
    __syncthreads();
    int n = blockIdx.x * 256 + tid;
    int k = idx[n];
    int lrank = atomicAdd(&hcnt[k], 1);
    __syncthreads();
    for (int i = tid; i < KCODE; i += 256) {
        int h = hcnt[i];
        if (h) hbase[i] = atomicAdd(&cursor[i], h);
    }
    __syncthreads();
    rowlist[hbase[k] + lrank] = n;
}

// FUSED segment-sum + quantize + loss: each block scans 128 rowlist entries
// (sorted by code). Per entry j: accumulate x-row into the per-code partial
// (flushed at code boundaries via atomics), emit q_st row = x + (ET[k]-x)
// (fp32, replicating reference rounding), accumulate loss (ET row register-
// cached per code-run). Removes the separate 64MB x re-read of the old
// vq_quantize_loss kernel. Loss partial scattered over 256 slots
// (round-4 lesson: single-address atomic convoy cost ~250 us).
__global__ void vq_chunksum(const float* __restrict__ x,
                            const int* __restrict__ rowlist,
                            const int* __restrict__ idx,
                            const float* __restrict__ ET,
                            float* __restrict__ sums,
                            float* __restrict__ out,
                            float* __restrict__ lpart) {
    __shared__ int rl[128];
    __shared__ int kk[128];
    __shared__ float wsum[2];
    int tid = threadIdx.x;   // 128 threads, tid == d
    int base = blockIdx.x * 128;
    int r = rowlist[base + tid];
    rl[tid] = r;
    kk[tid] = idx[r];
    __syncthreads();
    float s = 0.f, lossp = 0.f;
    int kprev = kk[0];
    float qreg = ET[(size_t)kprev * DIMD + tid];
    #pragma unroll 4
    for (int j = 0; j < 128; ++j) {
        int kj = kk[j];
        if (kj != kprev) {
            atomicAdd(&sums[(size_t)kprev * DIMD + tid], s);
            s = 0.f;
            kprev = kj;
            qreg = ET[(size_t)kj * DIMD + tid];
        }
        size_t off = (size_t)rl[j] * DIMD + tid;
        float xv = x[off];
        s += xv;
        float diff = qreg - xv;
        out[OUT_QST + off] = xv + diff;
        lossp = fmaf(diff, diff, lossp);
    }
    atomicAdd(&sums[(size_t)kprev * DIMD + tid], s);
    // loss reduction: 2 waves
    #pragma unroll
    for (int off = 32; off > 0; off >>= 1)
        lossp += __shfl_down(lossp, off);
    if ((tid & 63) == 0) wsum[tid >> 6] = lossp;
    __syncthreads();
    if (tid == 0)
        atomicAdd(&lpart[blockIdx.x & 255], wsum[0] + wsum[1]);
}

// EMA outputs from sums + counts; block 0 also reduces the 256 loss slots.
__global__ void vq_finalize_emb(const int* __restrict__ counts,
                                const float* __restrict__ sums,
                                const float* __restrict__ emc,
                                const float* __restrict__ es,
                                const float* __restrict__ lpart,
                                float* __restrict__ out) {
    int gid = blockIdx.x * 256 + threadIdx.x;   // 131072
    int k = gid & (KCODE - 1), d = gid >> 10;
    float cnt = (float)counts[k];
    float ecn = fmaf(0.85f, cnt, 0.15f * emc[k]);
    float esn = fmaf(0.85f, sums[(size_t)k * DIMD + d], 0.15f * es[(size_t)d * KCODE + k]);
    out[OUT_ES + (size_t)d * KCODE + k] = esn;
    out[OUT_EMB + (size_t)d * KCODE + k] = esn / fmaxf(ecn, 1e-5f);
    if (d == 0) out[OUT_CNT + k] = ecn;
    if (blockIdx.x == 0) {
        float v = lpart[threadIdx.x];   // 256 slots, 256 threads
        #pragma unroll
        for (int off = 32; off > 0; off >>= 1)
            v += __shfl_down(v, off);
        __shared__ float ws4[4];
        if ((threadIdx.x & 63) == 0) ws4[threadIdx.x >> 6] = v;
        __syncthreads();
        if (threadIdx.x == 0)
            out[OUT_LOSS] = (ws4[0] + ws4[1] + ws4[2] + ws4[3]) /
                            ((float)NROWS * (float)DIMD);  // BETA = 1
    }
}

// ============================================================
extern "C" void kernel_launch(void* const* d_in, const int* in_sizes, int n_in,
                              void* d_out, int out_size, void* d_ws, size_t ws_size,
                              hipStream_t stream) {
    const float* x   = (const float*)d_in[0];
    const float* E   = (const float*)d_in[1];
    const float* emc = (const float*)d_in[2];
    const float* es  = (const float*)d_in[3];
    float* out = (float*)d_out;
    char* ws = (char*)d_ws;

    int*    refine_cnt  = (int*)(ws + WS_REFINE_CNT);
    int*    counts      = (int*)(ws + WS_COUNTS);
    float*  sums        = (float*)(ws + WS_SUMS);
    float*  lpart       = (float*)(ws + WS_LPART);
    int*    cursor      = (int*)(ws + WS_CURSOR);
    float*  e2          = (float*)(ws + WS_E2);
    float*  ET          = (float*)(ws + WS_ET);
    uint4*  Bh          = (uint4*)(ws + WS_BHI);
    int*    idx         = (int*)(ws + WS_IDX);
    int*    rowlist     = (int*)(ws + WS_ROWLIST);
    int*    refine_pairs= (int*)(ws + WS_REFINE);

    // zero: refine counter, counts, sums, loss slots, cursor, e2
    hipMemsetAsync(ws, 0, WS_ZERO_BYTES, stream);

    vq_prep<<<64, 256, 0, stream>>>(E, Bh, ET, e2);
    vq_argmin_mfma<<<NROWS / 64, 256, 0, stream>>>(x, Bh, e2, idx, counts,
                                                   refine_pairs, refine_cnt);
    vq_refine2<<<256, 256, 0, stream>>>(x, ET, e2, refine_pairs, refine_cnt,
                                        idx, counts);
    vq_scan<<<1, KCODE, 0, stream>>>(counts, cursor);
    vq_fill<<<NROWS / 256, 256, 0, stream>>>(idx, cursor, rowlist);
    vq_chunksum<<<NROWS / 128, 128, 0, stream>>>(x, rowlist, idx, ET, sums,
                                                 out, lpart);
    vq_finalize_emb<<<(DIMD * KCODE) / 256, 256, 0, stream>>>(counts, sums, emc, es, lpart, out);
}

// Round 11
// 279.811 us; speedup vs baseline: 1.1302x; 1.1302x over previous
//
#include <hip/hip_runtime.h>
#include <cfloat>
#include <cstdint>

// Problem constants
#define NROWS 131072
#define DIMD  128
#define KCODE 1024
#define MARGIN 0.045f  // f16 single-pass gap error sigma ~9.6e-3 -> ~4.7 sigma
#define RCAP  65536    // refine capacity (pairs) in the N-int WS_REFINE region

typedef __attribute__((ext_vector_type(8))) _Float16 half8;  // 8 f16 = 4 VGPRs
typedef __attribute__((ext_vector_type(4))) float f32x4;

union U4H8 { uint4 u; half8 h; };

// ---- workspace layout (bytes); total ~3.23 MB ----
#define WS_REFINE_CNT 0         // int
#define WS_LOSS       8         // float (unused slot; layout stability)
#define WS_COUNTS     16        // int[1024]
#define WS_SUMS       4608      // float[K*D] = 512 KB (layout [k][d])
#define WS_LPART      528896    // float[256] loss partial slots (zeroed)
#define WS_CURSOR     532992    // int[1024]
#define WS_E2         537088    // float[1024]
#define WS_ZERO_BYTES 541184    // memset [0, WS_ZERO_BYTES) — covers e2 too
#define WS_ET         541184    // float[K*D] (ET[k][d])
#define WS_BHI        1065472   // uint4[16384] = 256 KB (f16 B fragments)
#define WS_BEST       1327616   // (unused; layout stability)
#define WS_IDX        1589760   // int[N]
#define WS_ROWLIST    2114048   // int[N]
#define WS_REFINE     2638336   // int[N] -> used as (row,i2) pairs, cap 65536
#define WS_PARTIALS   3162624   // float[16384] (unused; layout stability)
// end: 3228160 bytes

// ---- output offsets (in floats), reference return order ----
#define OUT_QST  ((size_t)0)
#define OUT_EMB  ((size_t)NROWS * DIMD)
#define OUT_CNT  (OUT_EMB + (size_t)DIMD * KCODE)
#define OUT_ES   (OUT_CNT + KCODE)
#define OUT_LOSS (OUT_ES + (size_t)DIMD * KCODE)

__device__ __forceinline__ unsigned f16pair(float a, float b) {
    union { _Float16 h[2]; unsigned u; } p;
    p.h[0] = (_Float16)a;
    p.h[1] = (_Float16)b;
    return p.u;
}

// ============================================================
// Fused prep: one pass over E producing (1) Bh MFMA B-fragments (f16),
// (2) ET[k][d] transpose, (3) e2[k] = sum_d E[d][k]^2 via atomics.
__global__ void vq_prep(const float* __restrict__ E, uint4* __restrict__ Bh,
                        float* __restrict__ ET, float* __restrict__ e2) {
    int gid = blockIdx.x * 256 + threadIdx.x;   // 0..16383 == fi
    int l = gid & 63;
    int t = (gid >> 6) & 3;
    int NB = gid >> 8;
    int n = NB * 16 + (l & 15);
    int k0 = t * 32 + (l >> 4) * 8;
    float v[8];
    float ss = 0.f;
    #pragma unroll
    for (int j = 0; j < 8; ++j) {
        v[j] = E[(size_t)(k0 + j) * KCODE + n];
        ss = fmaf(v[j], v[j], ss);
    }
    Bh[gid] = make_uint4(f16pair(v[0], v[1]), f16pair(v[2], v[3]),
                         f16pair(v[4], v[5]), f16pair(v[6], v[7]));
    float4* et4 = (float4*)(ET + (size_t)n * DIMD + k0);
    et4[0] = make_float4(v[0], v[1], v[2], v[3]);
    et4[1] = make_float4(v[4], v[5], v[6], v[7]);
    atomicAdd(&e2[n], ss);
}

// ============================================================
// Main kernel: per-row argmin_k ( ||e_k||^2 - 2 x.e_k ) via SINGLE-PASS f16
// MFMA. EXACT round-7 structure (hardware-verified: 101 us, VGPR 60,
// occ 34%): 256 threads = 4 waves, each wave owns 32 rows (2 m-tiles of
// 16), grid = NROWS/128 = 1024 blocks, 2-deep register B prefetch.
// launch_bounds(256,2): allocator unconstrained — r4/r8 lesson: forcing
// minWaves below natural VGPR footprint causes spills.
// Tracks (m1,i1,m2,i2); ambiguous rows -> top-2 exact fp32 re-check.

#define LOADB(bARR, ev_, nb_)                                     \
  { _Pragma("unroll")                                             \
    for (int t_ = 0; t_ < 4; ++t_)                                \
      bARR[t_] = Bh[((nb_) * 4 + t_) * 64 + l];                   \
    ev_ = e2[(nb_) * 16 + m]; }

#define COMPUTE_NB(nb_, bARR, ev_)                                           \
  {                                                                          \
    f32x4 acc[2];                                                            \
    _Pragma("unroll")                                                        \
    for (int mt_ = 0; mt_ < 2; ++mt_) acc[mt_] = (f32x4){0.f,0.f,0.f,0.f};   \
    _Pragma("unroll")                                                        \
    for (int t_ = 0; t_ < 4; ++t_) {                                         \
      U4H8 bh_; bh_.u = bARR[t_];                                            \
      _Pragma("unroll")                                                      \
      for (int mt_ = 0; mt_ < 2; ++mt_)                                      \
        acc[mt_] = __builtin_amdgcn_mfma_f32_16x16x32_f16(ah[mt_][t_], bh_.h,\
                                                          acc[mt_], 0, 0, 0);\
    }                                                                        \
    int col_ = (nb_) * 16 + m;                                               \
    _Pragma("unroll")                                                        \
    for (int mt_ = 0; mt_ < 2; ++mt_)                                        \
      _Pragma("unroll")                                                      \
      for (int r_ = 0; r_ < 4; ++r_) {                                       \
        float s_ = fmaf(-2.0f, acc[mt_][r_], ev_);                           \
        if (s_ < m1[mt_][r_]) {                                              \
          m2[mt_][r_] = m1[mt_][r_]; i2[mt_][r_] = i1[mt_][r_];              \
          m1[mt_][r_] = s_;          i1[mt_][r_] = col_;                     \
        } else if (s_ < m2[mt_][r_]) {                                       \
          m2[mt_][r_] = s_;          i2[mt_][r_] = col_;                     \
        }                                                                    \
      }                                                                      \
  }

__global__ __launch_bounds__(256, 2) void vq_argmin_mfma(
        const float* __restrict__ x, const uint4* __restrict__ Bh,
        const float* __restrict__ e2,
        int* __restrict__ idx, int* __restrict__ counts,
        int* __restrict__ refine_pairs, int* __restrict__ refine_cnt) {

    __shared__ int hist[KCODE];   // 4 KB (epilogue only)

    const int tid = threadIdx.x;
    const int w = tid >> 6, l = tid & 63;
    const int m = l & 15, q = l >> 4;
    const int rw = blockIdx.x * 128 + w * 32;

    // B prefetch prologue (in flight while the A-phase loads/converts)
    uint4 bA[4], bB[4];
    float evA, evB;
    LOADB(bA, evA, 0);
    LOADB(bB, evB, 1);

    // ---------- A-phase: f16 A-fragments straight from global ----------
    // lane (m,q) of m-tile mt holds x[rw+mt*16+m][t*32 + q*8 + j], j=0..7
    const float4* x4 = (const float4*)x;
    half8 ah[2][4];                 // [m-tile][k-tile]
    #pragma unroll
    for (int mt = 0; mt < 2; ++mt) {
        int row = rw + mt * 16 + m;
        #pragma unroll
        for (int t = 0; t < 4; ++t) {
            int c4 = t * 8 + q * 2;
            float4 va = x4[(size_t)row * 32 + c4];
            float4 vb = x4[(size_t)row * 32 + c4 + 1];
            half8 hh;
            hh[0] = (_Float16)va.x; hh[1] = (_Float16)va.y;
            hh[2] = (_Float16)va.z; hh[3] = (_Float16)va.w;
            hh[4] = (_Float16)vb.x; hh[5] = (_Float16)vb.y;
            hh[6] = (_Float16)vb.z; hh[7] = (_Float16)vb.w;
            ah[mt][t] = hh;
        }
    }

    float m1[2][4], m2[2][4];
    int i1[2][4], i2[2][4];
    #pragma unroll
    for (int a = 0; a < 2; ++a)
        #pragma unroll
        for (int r = 0; r < 4; ++r) {
            m1[a][r] = FLT_MAX; m2[a][r] = FLT_MAX;
            i1[a][r] = 0; i2[a][r] = 0;
        }

    // ---------- K-loop over 64 n-blocks of 16 codes, barrier-free ----------
    for (int nb = 0; nb < 64; nb += 2) {
        COMPUTE_NB(nb, bA, evA);
        { int p = (nb + 2 <= 63) ? nb + 2 : 62; LOADB(bA, evA, p); }
        COMPUTE_NB(nb + 1, bB, evB);
        { int p = (nb + 3 <= 63) ? nb + 3 : 63; LOADB(bB, evB, p); }
    }

    // ---------- merge across the 16 lanes of each quad ----------
    // Full (m1,i1,m2,i2) lexicographic merge.
    #pragma unroll
    for (int mt = 0; mt < 2; ++mt)
        #pragma unroll
        for (int r = 0; r < 4; ++r) {
            float a1 = m1[mt][r], a2 = m2[mt][r];
            int ai1 = i1[mt][r], ai2 = i2[mt][r];
            #pragma unroll
            for (int off = 1; off < 16; off <<= 1) {
                float o1 = __shfl_xor(a1, off, 64);
                float o2 = __shfl_xor(a2, off, 64);
                int oi1 = __shfl_xor(ai1, off, 64);
                int oi2 = __shfl_xor(ai2, off, 64);
                // winner of firsts (lex, first-index ties)
                bool take = (o1 < a1) || (o1 == a1 && oi1 < ai1);
                float w1 = take ? o1 : a1;  int wi1 = take ? oi1 : ai1;
                float l1 = take ? a1 : o1;  int li1 = take ? ai1 : oi1;
                // second = lexmin{ (a2,ai2), (o2,oi2), (l1,li1) }
                float c2 = a2; int ci2 = ai2;
                if (o2 < c2 || (o2 == c2 && oi2 < ci2)) { c2 = o2; ci2 = oi2; }
                if (l1 < c2 || (l1 == c2 && li1 < ci2)) { c2 = l1; ci2 = li1; }
                a1 = w1; ai1 = wi1; a2 = c2; ai2 = ci2;
            }
            m1[mt][r] = a1; m2[mt][r] = a2;
            i1[mt][r] = ai1; i2[mt][r] = ai2;
        }

    // ---------- write idx, LDS-aggregated histogram, refine pairs ----------
    for (int i = tid; i < KCODE; i += 256) hist[i] = 0;
    __syncthreads();
    if (m == 0) {   // 4 representative lanes per wave (one per quad)
        #pragma unroll
        for (int mt = 0; mt < 2; ++mt)
            #pragma unroll
            for (int r = 0; r < 4; ++r) {
                int row = rw + mt * 16 + q * 4 + r;
                int bi = i1[mt][r];
                idx[row] = bi;
                atomicAdd(&hist[bi], 1);
                if (!(m2[mt][r] - m1[mt][r] > MARGIN)) {
                    int pos = atomicAdd(refine_cnt, 1);
                    if (pos < RCAP) {
                        refine_pairs[2 * pos]     = row;
                        refine_pairs[2 * pos + 1] = i2[mt][r];
                    }
                }
            }
    }
    __syncthreads();
    for (int i = tid; i < KCODE; i += 256) {
        int h = hist[i];
        if (h) atomicAdd(&counts[i], h);
    }
}

// ============================================================
// Top-2 exact re-check: for each ambiguous row, compute exact fp32 distances
// for the two f16 candidates (ET rows are contiguous 512 B) and keep the
// lex-min. O(cnt * 256 FMA). Thread-per-entry, no LDS.
__global__ __launch_bounds__(256) void vq_refine2(
        const float* __restrict__ x, const float* __restrict__ ET,
        const float* __restrict__ e2,
        const int* __restrict__ refine_pairs, const int* __restrict__ refine_cnt,
        int* __restrict__ idx, int* __restrict__ counts) {
    int cnt = *refine_cnt;
    if (cnt > RCAP) cnt = RCAP;
    for (int e = blockIdx.x * 256 + threadIdx.x; e < cnt; e += gridDim.x * 256) {
        int n  = refine_pairs[2 * e];
        int kb = refine_pairs[2 * e + 1];
        int ka = idx[n];
        const float4* xa = (const float4*)(x + (size_t)n * DIMD);
        const float4* ea = (const float4*)(ET + (size_t)ka * DIMD);
        const float4* eb = (const float4*)(ET + (size_t)kb * DIMD);
        float da = 0.f, db = 0.f;
        #pragma unroll 8
        for (int d4 = 0; d4 < DIMD / 4; ++d4) {
            float4 xv = xa[d4];
            float4 av = ea[d4];
            float4 bv = eb[d4];
            da = fmaf(xv.x, av.x, da); da = fmaf(xv.y, av.y, da);
            da = fmaf(xv.z, av.z, da); da = fmaf(xv.w, av.w, da);
            db = fmaf(xv.x, bv.x, db); db = fmaf(xv.y, bv.y, db);
            db = fmaf(xv.z, bv.z, db); db = fmaf(xv.w, bv.w, db);
        }
        float sa = fmaf(-2.0f, da, e2[ka]);
        float sb = fmaf(-2.0f, db, e2[kb]);
        bool swap = (sb < sa) || (sb == sa && kb < ka);   // first-index ties
        if (swap) {
            idx[n] = kb;
            atomicSub(&counts[ka], 1);
            atomicAdd(&counts[kb], 1);
        }
    }
}

// ============================================================
__global__ void vq_scan(const int* __restrict__ counts, int* __restrict__ cursor) {
    __shared__ int s[KCODE];
    int t = threadIdx.x;
    int c = counts[t];
    s[t] = c;
    __syncthreads();
    for (int off = 1; off < KCODE; off <<= 1) {
        int v = (t >= off) ? s[t - off] : 0;
        __syncthreads();
        s[t] += v;
        __syncthreads();
    }
    cursor[t] = s[t] - c;
}

// LDS-aggregated bucket fill (kills same-address global atomic chains)
__global__ void vq_fill(const int* __restrict__ idx, int* __restrict__ cursor,
                        int* __restrict__ rowlist) {
    __shared__ int hcnt[KCODE];
    __shared__ int hbase[KCODE];
    int tid = threadIdx.x;
    for (int i = tid; i < KCODE; i += 256) hcnt[i] = 0;
    __syncthreads();
    int n = blockIdx.x * 256 + tid;
    int k = idx[n];
    int lrank = atomicAdd(&hcnt[k], 1);
    __syncthreads();
    for (int i = tid; i < KCODE; i += 256) {
        int h = hcnt[i];
        if (h) hbase[i] = atomicAdd(&cursor[i], h);
    }
    __syncthreads();
    rowlist[hbase[k] + lrank] = n;
}

// FUSED segment-sum + quantize + loss: each block scans 128 rowlist entries
// (sorted by code). Per entry j: accumulate x-row into the per-code partial
// (flushed at code boundaries via atomics), emit q_st row = x + (ET[k]-x)
// (fp32, replicating reference rounding), accumulate loss (ET row register-
// cached per code-run). Loss partial scattered over 256 slots (round-4
// lesson: single-address atomic convoy cost ~250 us).
__global__ void vq_chunksum(const float* __restrict__ x,
                            const int* __restrict__ rowlist,
                            const int* __restrict__ idx,
                            const float* __restrict__ ET,
                            float* __restrict__ sums,
                            float* __restrict__ out,
                            float* __restrict__ lpart) {
    __shared__ int rl[128];
    __shared__ int kk[128];
    __shared__ float wsum[2];
    int tid = threadIdx.x;   // 128 threads, tid == d
    int base = blockIdx.x * 128;
    int r = rowlist[base + tid];
    rl[tid] = r;
    kk[tid] = idx[r];
    __syncthreads();
    float s = 0.f, lossp = 0.f;
    int kprev = kk[0];
    float qreg = ET[(size_t)kprev * DIMD + tid];
    #pragma unroll 4
    for (int j = 0; j < 128; ++j) {
        int kj = kk[j];
        if (kj != kprev) {
            atomicAdd(&sums[(size_t)kprev * DIMD + tid], s);
            s = 0.f;
            kprev = kj;
            qreg = ET[(size_t)kj * DIMD + tid];
        }
        size_t off = (size_t)rl[j] * DIMD + tid;
        float xv = x[off];
        s += xv;
        float diff = qreg - xv;
        out[OUT_QST + off] = xv + diff;
        lossp = fmaf(diff, diff, lossp);
    }
    atomicAdd(&sums[(size_t)kprev * DIMD + tid], s);
    // loss reduction: 2 waves
    #pragma unroll
    for (int off = 32; off > 0; off >>= 1)
        lossp += __shfl_down(lossp, off);
    if ((tid & 63) == 0) wsum[tid >> 6] = lossp;
    __syncthreads();
    if (tid == 0)
        atomicAdd(&lpart[blockIdx.x & 255], wsum[0] + wsum[1]);
}

// EMA outputs from sums + counts; block 0 also reduces the 256 loss slots.
__global__ void vq_finalize_emb(const int* __restrict__ counts,
                                const float* __restrict__ sums,
                                const float* __restrict__ emc,
                                const float* __restrict__ es,
                                const float* __restrict__ lpart,
                                float* __restrict__ out) {
    int gid = blockIdx.x * 256 + threadIdx.x;   // 131072
    int k = gid & (KCODE - 1), d = gid >> 10;
    float cnt = (float)counts[k];
    float ecn = fmaf(0.85f, cnt, 0.15f * emc[k]);
    float esn = fmaf(0.85f, sums[(size_t)k * DIMD + d], 0.15f * es[(size_t)d * KCODE + k]);
    out[OUT_ES + (size_t)d * KCODE + k] = esn;
    out[OUT_EMB + (size_t)d * KCODE + k] = esn / fmaxf(ecn, 1e-5f);
    if (d == 0) out[OUT_CNT + k] = ecn;
    if (blockIdx.x == 0) {
        float v = lpart[threadIdx.x];   // 256 slots, 256 threads
        #pragma unroll
        for (int off = 32; off > 0; off >>= 1)
            v += __shfl_down(v, off);
        __shared__ float ws4[4];
        if ((threadIdx.x & 63) == 0) ws4[threadIdx.x >> 6] = v;
        __syncthreads();
        if (threadIdx.x == 0)
            out[OUT_LOSS] = (ws4[0] + ws4[1] + ws4[2] + ws4[3]) /
                            ((float)NROWS * (float)DIMD);  // BETA = 1
    }
}

// ============================================================
extern "C" void kernel_launch(void* const* d_in, const int* in_sizes, int n_in,
                              void* d_out, int out_size, void* d_ws, size_t ws_size,
                              hipStream_t stream) {
    const float* x   = (const float*)d_in[0];
    const float* E   = (const float*)d_in[1];
    const float* emc = (const float*)d_in[2];
    const float* es  = (const float*)d_in[3];
    float* out = (float*)d_out;
    char* ws = (char*)d_ws;

    int*    refine_cnt  = (int*)(ws + WS_REFINE_CNT);
    int*    counts      = (int*)(ws + WS_COUNTS);
    float*  sums        = (float*)(ws + WS_SUMS);
    float*  lpart       = (float*)(ws + WS_LPART);
    int*    cursor      = (int*)(ws + WS_CURSOR);
    float*  e2          = (float*)(ws + WS_E2);
    float*  ET          = (float*)(ws + WS_ET);
    uint4*  Bh          = (uint4*)(ws + WS_BHI);
    int*    idx         = (int*)(ws + WS_IDX);
    int*    rowlist     = (int*)(ws + WS_ROWLIST);
    int*    refine_pairs= (int*)(ws + WS_REFINE);

    // zero: refine counter, counts, sums, loss slots, cursor, e2
    hipMemsetAsync(ws, 0, WS_ZERO_BYTES, stream);

    vq_prep<<<64, 256, 0, stream>>>(E, Bh, ET, e2);
    vq_argmin_mfma<<<NROWS / 128, 256, 0, stream>>>(x, Bh, e2, idx, counts,
                                                    refine_pairs, refine_cnt);
    vq_refine2<<<256, 256, 0, stream>>>(x, ET, e2, refine_pairs, refine_cnt,
                                        idx, counts);
    vq_scan<<<1, KCODE, 0, stream>>>(counts, cursor);
    vq_fill<<<NROWS / 256, 256, 0, stream>>>(idx, cursor, rowlist);
    vq_chunksum<<<NROWS / 128, 128, 0, stream>>>(x, rowlist, idx, ET, sums,
                                                 out, lpart);
    vq_finalize_emb<<<(DIMD * KCODE) / 256, 256, 0, stream>>>(counts, sums, emc, es, lpart, out);
}